// Round 10
// baseline (447.547 us; speedup 1.0000x reference)
//
#include <hip/hip_runtime.h>

// ---------------------------------------------------------------------------
// Pipeline:
//  k_prep : w2[64,32,3] -> w2t[3,32,64]; wfc[512,64] -> wB{h,m,l} bf16
//           3-way-split B-fragments in MFMA order [n][s][lane][j]
//  kA     : h[v] = mean_j relu(conv3_j(vp[nb1[v,:]]))               [V]
//  kB     : f1[v,o] = h[v-1]*w1[o,0]+h[v]*w1[o,1]+h[v+1]*w1[o,2]+b1 [V,32]
//  kC     : h2[v,c] = mean_j relu(conv3_j(f1[nb2[v,j],c]))          [V,32]
//  kD     : f2[v,o] = sum_{k,c} h2[v-1+k,c]*w2t[k,c,o] + b2[o]      [V,64]
//  kE     : out[v,:] = softmax(f2[v,:] @ wfc^T + bfc)               [V,512]
//
// R13 change (kC only; R9's two tweaks were both null -> kC is not
// marginally VMEM-instr-bound, test the float4-lane structure):
//  kC: ONE VERTEX PER WAVE, lane=(jq=l>>3, seg=l&7), float4/lane.
//      Each gather instr covers 8 random 128B rows (8 lanes x 16B = a
//      row); 4 instrs fetch all 32 rows (was 32 instrs @ 2 rows).
//      Same bytes, 8x fewer VMEM instrs, all 4 issued back-to-back.
//      Conv j+-1 via shfl +-8; group edges via 2 variable shfls; channel
//      sum via shfl_xor over the 8 jq lanes; lanes 0-7 store float4
//      (128B/vertex coalesced). ~40 VGPR, no spill, no forced bounds.
//      Predict: kC latency-bound -> -30..50us total; null -> kC is
//      L2/L3 row-BW bound, pivot to shrinking f1.
// ---------------------------------------------------------------------------

typedef short bf16x8 __attribute__((ext_vector_type(8)));
typedef float f32x4 __attribute__((ext_vector_type(4)));

__device__ inline unsigned short f2bf(float x) {
    unsigned u = __float_as_uint(x);
    unsigned r = (u + 0x7FFFu + ((u >> 16) & 1u)) >> 16;
    return (unsigned short)r;
}
__device__ inline float bf2f(unsigned short b) {
    return __uint_as_float(((unsigned)b) << 16);
}

// k_prep: w2 transpose + wfc -> 3-way bf16 split in B-fragment order.
__global__ __launch_bounds__(256) void k_prep(const float* __restrict__ wfc,
                                              const float* __restrict__ w2,
                                              short* __restrict__ wBh,
                                              short* __restrict__ wBm,
                                              short* __restrict__ wBl,
                                              float* __restrict__ w2t) {
    int t = blockIdx.x * 256 + threadIdx.x;
    if (t < 32768) {
        int j = t & 7;
        int l = (t >> 3) & 63;
        int s = (t >> 9) & 1;
        int n = t >> 10;
        int col = n * 16 + (l & 15);
        int k = s * 32 + (l >> 4) * 8 + j;
        float v = wfc[col * 64 + k];
        unsigned short h = f2bf(v);
        float r1 = v - bf2f(h);
        unsigned short m = f2bf(r1);
        float r2 = r1 - bf2f(m);
        wBh[t] = (short)h;
        wBm[t] = (short)m;
        wBl[t] = (short)f2bf(r2);
    } else if (t < 32768 + 6144) {
        int i = t - 32768;
        int o = i / 96;
        int r = i - o * 96;
        int c = r / 3;
        int k = r - c * 3;
        w2t[(k * 32 + c) * 64 + o] = w2[i];
    }
}

// conv1 over neighbor axis: one 32-lane segment per vertex
__global__ __launch_bounds__(256) void kA(const float* __restrict__ vp,
                                          const int* __restrict__ nb1,
                                          const float* __restrict__ wv1,
                                          const float* __restrict__ bv1,
                                          float* __restrict__ h, int V) {
    int t = blockIdx.x * 256 + threadIdx.x;
    int v = t >> 5;
    int j = t & 31;
    if (v >= V) return;
    float g = vp[nb1[v * 32 + j]];
    float gm = __shfl_up(g, 1, 32);
    if (j == 0) gm = 0.0f;
    float gp = __shfl_down(g, 1, 32);
    if (j == 31) gp = 0.0f;
    float c = wv1[0] * gm + wv1[1] * g + wv1[2] * gp + bv1[0];
    c = fmaxf(c, 0.0f);
    #pragma unroll
    for (int off = 16; off; off >>= 1) c += __shfl_xor(c, off, 32);
    if (j == 0) h[v] = c * (1.0f / 32.0f);
}

// vertex-shift 3-tap mix into 32 channels
__global__ __launch_bounds__(256) void kB(const float* __restrict__ h,
                                          const float* __restrict__ w1,
                                          const float* __restrict__ b1,
                                          float* __restrict__ f1, int V) {
    int t = blockIdx.x * 256 + threadIdx.x;
    int v = t >> 5;
    int o = t & 31;
    if (v >= V) return;
    float hm = (v > 0) ? h[v - 1] : 0.0f;
    float h0 = h[v];
    float hp = (v + 1 < V) ? h[v + 1] : 0.0f;
    f1[v * 32 + o] = fmaf(hm, w1[o * 3 + 0],
                     fmaf(h0, w1[o * 3 + 1],
                     fmaf(hp, w1[o * 3 + 2], b1[o])));
}

// conv2: one vertex per WAVE. lane l: seg=l&7 (channels seg*4..+3),
// jq=l>>3. 4 float4 gathers fetch all 32 neighbor rows (8 rows/instr).
// Conv along j: shfl +-8 in-wave, group edges via variable shfl; sum
// over j = shfl_xor over the 8 jq lanes; lanes 0-7 store float4.
__global__ __launch_bounds__(256) void kC(const float* __restrict__ f1,
                                          const int* __restrict__ nb2,
                                          const float* __restrict__ wv2,
                                          const float* __restrict__ bv2,
                                          float* __restrict__ h2, int V) {
    int t = threadIdx.x;
    int l = t & 63;
    int v = blockIdx.x * 4 + (t >> 6);   // one vertex per wave
    if (v >= V) return;
    int seg = l & 7;
    int jq  = l >> 3;

    int nbl = nb2[(size_t)v * 32 + (l & 31)];   // both halves hold nb[0..31]

    int i0 = __shfl(nbl,  0 + jq, 64);
    int i1 = __shfl(nbl,  8 + jq, 64);
    int i2 = __shfl(nbl, 16 + jq, 64);
    int i3 = __shfl(nbl, 24 + jq, 64);
    float4 x0 = *(const float4*)(f1 + (size_t)i0 * 32 + seg * 4);
    float4 x1 = *(const float4*)(f1 + (size_t)i1 * 32 + seg * 4);
    float4 x2 = *(const float4*)(f1 + (size_t)i2 * 32 + seg * 4);
    float4 x3 = *(const float4*)(f1 + (size_t)i3 * 32 + seg * 4);

    float w0 = wv2[0], w1_ = wv2[1], w2_ = wv2[2], b = bv2[0];
    float s0 = 0.f, s1 = 0.f, s2 = 0.f, s3 = 0.f;

    // For group cur with prev-group scalar XP and next-group scalar XN:
    // pv = jq>0 ? shfl_up(cur,8) : (first ? 0 : shfl(XP, 56+seg))
    // nx = jq<7 ? shfl_down(cur,8) : (last ? 0 : shfl(XN, seg))
#define TAP(SACC, CUR, XP, XN, FIRST, LAST) { \
        float pvs = __shfl_up(CUR, 8);   /* width 64 */ \
        float nxs = __shfl_down(CUR, 8); \
        float pve = (FIRST) ? 0.0f : __shfl((XP), 56 + seg, 64); \
        float nxe = (LAST)  ? 0.0f : __shfl((XN), seg, 64); \
        float pv = (jq == 0) ? pve : pvs; \
        float nx = (jq == 7) ? nxe : nxs; \
        float cv = fmaf(w0, pv, fmaf(w1_, (CUR), fmaf(w2_, nx, b))); \
        SACC += fmaxf(cv, 0.0f); }

    TAP(s0, x0.x, x0.x, x1.x, 1, 0)  TAP(s0, x1.x, x0.x, x2.x, 0, 0)
    TAP(s0, x2.x, x1.x, x3.x, 0, 0)  TAP(s0, x3.x, x2.x, x3.x, 0, 1)
    TAP(s1, x0.y, x0.y, x1.y, 1, 0)  TAP(s1, x1.y, x0.y, x2.y, 0, 0)
    TAP(s1, x2.y, x1.y, x3.y, 0, 0)  TAP(s1, x3.y, x2.y, x3.y, 0, 1)
    TAP(s2, x0.z, x0.z, x1.z, 1, 0)  TAP(s2, x1.z, x0.z, x2.z, 0, 0)
    TAP(s2, x2.z, x1.z, x3.z, 0, 0)  TAP(s2, x3.z, x2.z, x3.z, 0, 1)
    TAP(s3, x0.w, x0.w, x1.w, 1, 0)  TAP(s3, x1.w, x0.w, x2.w, 0, 0)
    TAP(s3, x2.w, x1.w, x3.w, 0, 0)  TAP(s3, x3.w, x2.w, x3.w, 0, 1)
#undef TAP

    // sum over the 8 jq lanes (stride 8): lanes {seg, seg+8, ..., seg+56}
    #pragma unroll
    for (int off = 8; off <= 32; off <<= 1) {
        s0 += __shfl_xor(s0, off);
        s1 += __shfl_xor(s1, off);
        s2 += __shfl_xor(s2, off);
        s3 += __shfl_xor(s3, off);
    }

    if (jq == 0) {
        float4 r = make_float4(s0 * (1.0f / 32.0f), s1 * (1.0f / 32.0f),
                               s2 * (1.0f / 32.0f), s3 * (1.0f / 32.0f));
        *(float4*)(h2 + (size_t)v * 32 + seg * 4) = r;
    }
}

// f2 einsum: 256 threads / 32 vertices per block, h2 halo tile in LDS.
__global__ __launch_bounds__(256) void kD(const float* __restrict__ h2,
                                          const float* __restrict__ w2t,
                                          const float* __restrict__ b2,
                                          float* __restrict__ f2, int V) {
    __shared__ float tile[34 * 32];     // 4.25 KB, rows v0-1 .. v0+32
    int t = threadIdx.x;
    int v0 = blockIdx.x * 32;

    for (int i = t; i < 272; i += 256) {
        int r = i >> 3;
        int s = i & 7;
        int v = v0 - 1 + r;
        float4 val = make_float4(0.f, 0.f, 0.f, 0.f);
        if (v >= 0 && v < V)
            val = *(const float4*)(h2 + (size_t)v * 32 + s * 4);
        *(float4*)(tile + r * 32 + s * 4) = val;
    }
    __syncthreads();

    int o = t & 63;
    int w = t >> 6;
    int vb = w * 8;
    float bo = b2[o];
    float acc[8];
    #pragma unroll
    for (int m = 0; m < 8; ++m) acc[m] = bo;

    #pragma unroll
    for (int c4 = 0; c4 < 8; ++c4) {
        float4 hv[10];
        #pragma unroll
        for (int r = 0; r < 10; ++r)
            hv[r] = *(const float4*)(tile + (vb + r) * 32 + c4 * 4);
        #pragma unroll
        for (int k = 0; k < 3; ++k) {
            #pragma unroll
            for (int cc = 0; cc < 4; ++cc) {
                int c = c4 * 4 + cc;
                float wv = w2t[(k * 32 + c) * 64 + o];
                #pragma unroll
                for (int m = 0; m < 8; ++m) {
                    float hval = (cc == 0) ? hv[m + k].x :
                                 (cc == 1) ? hv[m + k].y :
                                 (cc == 2) ? hv[m + k].z : hv[m + k].w;
                    acc[m] = fmaf(hval, wv, acc[m]);
                }
            }
        }
    }
    #pragma unroll
    for (int m = 0; m < 8; ++m) {
        int v = v0 + vb + m;
        if (v < V) f2[(size_t)v * 64 + o] = acc[m];
    }
}

// fc + softmax on the MATRIX pipe. 256 thr / 32 vertices / block.
// Two A-row-sets per wave; each B frag load feeds 24 MFMAs.
// C/D: col=lane&15, row=(lane>>4)*4+reg.
__global__ __launch_bounds__(256) void kE(const float* __restrict__ f2,
                                          const short* __restrict__ wBh,
                                          const short* __restrict__ wBm,
                                          const short* __restrict__ wBl,
                                          const float* __restrict__ bfc,
                                          float* __restrict__ out, int V) {
    __shared__ float redmax[4][32];
    __shared__ float redsum[4][32];
    int t = threadIdx.x;
    int w = t >> 6;          // wave 0..3
    int l = t & 63;          // lane
    int c16 = l & 15;
    int g = l >> 4;          // K-group / row-group
    int vbase = blockIdx.x * 32;   // V % 32 == 0

    // ---- A fragments: two row-sets, 3-way bf16 split ----
    bf16x8 ah0[2], am0[2], al0[2], ah1[2], am1[2], al1[2];
#define SPLIT(AH, AM, AL, idx, x) { \
        float xx = (x); \
        unsigned short h_ = f2bf(xx); \
        float r1_ = xx - bf2f(h_); \
        unsigned short m_ = f2bf(r1_); \
        float r2_ = r1_ - bf2f(m_); \
        AH[idx] = (short)h_; AM[idx] = (short)m_; AL[idx] = (short)f2bf(r2_); }
    #pragma unroll
    for (int set = 0; set < 2; ++set) {
        const float* rowp = f2 + (size_t)(vbase + set * 16 + c16) * 64 + g * 8;
        float4 q0 = *(const float4*)(rowp);        // s=0, k=g*8..+3
        float4 q1 = *(const float4*)(rowp + 4);    // s=0, k=g*8+4..+7
        float4 q2 = *(const float4*)(rowp + 32);   // s=1
        float4 q3 = *(const float4*)(rowp + 36);
        SPLIT(ah0[set], am0[set], al0[set], 0, q0.x)
        SPLIT(ah0[set], am0[set], al0[set], 1, q0.y)
        SPLIT(ah0[set], am0[set], al0[set], 2, q0.z)
        SPLIT(ah0[set], am0[set], al0[set], 3, q0.w)
        SPLIT(ah0[set], am0[set], al0[set], 4, q1.x)
        SPLIT(ah0[set], am0[set], al0[set], 5, q1.y)
        SPLIT(ah0[set], am0[set], al0[set], 6, q1.z)
        SPLIT(ah0[set], am0[set], al0[set], 7, q1.w)
        SPLIT(ah1[set], am1[set], al1[set], 0, q2.x)
        SPLIT(ah1[set], am1[set], al1[set], 1, q2.y)
        SPLIT(ah1[set], am1[set], al1[set], 2, q2.z)
        SPLIT(ah1[set], am1[set], al1[set], 3, q2.w)
        SPLIT(ah1[set], am1[set], al1[set], 4, q3.x)
        SPLIT(ah1[set], am1[set], al1[set], 5, q3.y)
        SPLIT(ah1[set], am1[set], al1[set], 6, q3.z)
        SPLIT(ah1[set], am1[set], al1[set], 7, q3.w)
    }
#undef SPLIT

    // ---- MFMA: 8 N-tiles per wave, 2 K-steps, 6 products, 2 row-sets ----
    f32x4 accA[8], accB[8];
    const bf16x8* Bh = (const bf16x8*)wBh;
    const bf16x8* Bm = (const bf16x8*)wBm;
    const bf16x8* Bl = (const bf16x8*)wBl;
    #pragma unroll
    for (int n8 = 0; n8 < 8; ++n8) {
        int n = w * 8 + n8;
        bf16x8 bh0 = Bh[(n * 2 + 0) * 64 + l];
        bf16x8 bm0 = Bm[(n * 2 + 0) * 64 + l];
        bf16x8 bl0 = Bl[(n * 2 + 0) * 64 + l];
        bf16x8 bh1 = Bh[(n * 2 + 1) * 64 + l];
        bf16x8 bm1 = Bm[(n * 2 + 1) * 64 + l];
        bf16x8 bl1 = Bl[(n * 2 + 1) * 64 + l];
        float bn = bfc[n * 16 + c16];
        f32x4 cA = {0.f, 0.f, 0.f, 0.f};
        cA = __builtin_amdgcn_mfma_f32_16x16x32_bf16(ah0[0], bh0, cA, 0, 0, 0);
        cA = __builtin_amdgcn_mfma_f32_16x16x32_bf16(ah0[0], bm0, cA, 0, 0, 0);
        cA = __builtin_amdgcn_mfma_f32_16x16x32_bf16(am0[0], bh0, cA, 0, 0, 0);
        cA = __builtin_amdgcn_mfma_f32_16x16x32_bf16(ah0[0], bl0, cA, 0, 0, 0);
        cA = __builtin_amdgcn_mfma_f32_16x16x32_bf16(am0[0], bm0, cA, 0, 0, 0);
        cA = __builtin_amdgcn_mfma_f32_16x16x32_bf16(al0[0], bh0, cA, 0, 0, 0);
        cA = __builtin_amdgcn_mfma_f32_16x16x32_bf16(ah1[0], bh1, cA, 0, 0, 0);
        cA = __builtin_amdgcn_mfma_f32_16x16x32_bf16(ah1[0], bm1, cA, 0, 0, 0);
        cA = __builtin_amdgcn_mfma_f32_16x16x32_bf16(am1[0], bh1, cA, 0, 0, 0);
        cA = __builtin_amdgcn_mfma_f32_16x16x32_bf16(ah1[0], bl1, cA, 0, 0, 0);
        cA = __builtin_amdgcn_mfma_f32_16x16x32_bf16(am1[0], bm1, cA, 0, 0, 0);
        cA = __builtin_amdgcn_mfma_f32_16x16x32_bf16(al1[0], bh1, cA, 0, 0, 0);
        cA.x += bn; cA.y += bn; cA.z += bn; cA.w += bn;
        accA[n8] = cA;
        f32x4 cB = {0.f, 0.f, 0.f, 0.f};
        cB = __builtin_amdgcn_mfma_f32_16x16x32_bf16(ah0[1], bh0, cB, 0, 0, 0);
        cB = __builtin_amdgcn_mfma_f32_16x16x32_bf16(ah0[1], bm0, cB, 0, 0, 0);
        cB = __builtin_amdgcn_mfma_f32_16x16x32_bf16(am0[1], bh0, cB, 0, 0, 0);
        cB = __builtin_amdgcn_mfma_f32_16x16x32_bf16(ah0[1], bl0, cB, 0, 0, 0);
        cB = __builtin_amdgcn_mfma_f32_16x16x32_bf16(am0[1], bm0, cB, 0, 0, 0);
        cB = __builtin_amdgcn_mfma_f32_16x16x32_bf16(al0[1], bh0, cB, 0, 0, 0);
        cB = __builtin_amdgcn_mfma_f32_16x16x32_bf16(ah1[1], bh1, cB, 0, 0, 0);
        cB = __builtin_amdgcn_mfma_f32_16x16x32_bf16(ah1[1], bm1, cB, 0, 0, 0);
        cB = __builtin_amdgcn_mfma_f32_16x16x32_bf16(am1[1], bh1, cB, 0, 0, 0);
        cB = __builtin_amdgcn_mfma_f32_16x16x32_bf16(ah1[1], bl1, cB, 0, 0, 0);
        cB = __builtin_amdgcn_mfma_f32_16x16x32_bf16(am1[1], bm1, cB, 0, 0, 0);
        cB = __builtin_amdgcn_mfma_f32_16x16x32_bf16(al1[1], bh1, cB, 0, 0, 0);
        cB.x += bn; cB.y += bn; cB.z += bn; cB.w += bn;
        accB[n8] = cB;
    }

    // ---- softmax: per reg j, set s: row = s*16 + g*4 + j ----
    float mA0 = -1e30f, mA1 = -1e30f, mA2 = -1e30f, mA3 = -1e30f;
    float mB0 = -1e30f, mB1 = -1e30f, mB2 = -1e30f, mB3 = -1e30f;
    #pragma unroll
    for (int n8 = 0; n8 < 8; ++n8) {
        mA0 = fmaxf(mA0, accA[n8].x); mA1 = fmaxf(mA1, accA[n8].y);
        mA2 = fmaxf(mA2, accA[n8].z); mA3 = fmaxf(mA3, accA[n8].w);
        mB0 = fmaxf(mB0, accB[n8].x); mB1 = fmaxf(mB1, accB[n8].y);
        mB2 = fmaxf(mB2, accB[n8].z); mB3 = fmaxf(mB3, accB[n8].w);
    }
    #pragma unroll
    for (int off = 8; off; off >>= 1) {
        mA0 = fmaxf(mA0, __shfl_xor(mA0, off));
        mA1 = fmaxf(mA1, __shfl_xor(mA1, off));
        mA2 = fmaxf(mA2, __shfl_xor(mA2, off));
        mA3 = fmaxf(mA3, __shfl_xor(mA3, off));
        mB0 = fmaxf(mB0, __shfl_xor(mB0, off));
        mB1 = fmaxf(mB1, __shfl_xor(mB1, off));
        mB2 = fmaxf(mB2, __shfl_xor(mB2, off));
        mB3 = fmaxf(mB3, __shfl_xor(mB3, off));
    }
    if (c16 == 0) {
        redmax[w][g * 4 + 0] = mA0;  redmax[w][g * 4 + 1] = mA1;
        redmax[w][g * 4 + 2] = mA2;  redmax[w][g * 4 + 3] = mA3;
        redmax[w][16 + g * 4 + 0] = mB0;  redmax[w][16 + g * 4 + 1] = mB1;
        redmax[w][16 + g * 4 + 2] = mB2;  redmax[w][16 + g * 4 + 3] = mB3;
    }
    __syncthreads();
#define GMAX(r) fmaxf(fmaxf(redmax[0][r], redmax[1][r]), \
                      fmaxf(redmax[2][r], redmax[3][r]))
    float gA0 = GMAX(g * 4 + 0), gA1 = GMAX(g * 4 + 1);
    float gA2 = GMAX(g * 4 + 2), gA3 = GMAX(g * 4 + 3);
    float gB0 = GMAX(16 + g * 4 + 0), gB1 = GMAX(16 + g * 4 + 1);
    float gB2 = GMAX(16 + g * 4 + 2), gB3 = GMAX(16 + g * 4 + 3);
#undef GMAX

    float sA0 = 0.f, sA1 = 0.f, sA2 = 0.f, sA3 = 0.f;
    float sB0 = 0.f, sB1 = 0.f, sB2 = 0.f, sB3 = 0.f;
    #pragma unroll
    for (int n8 = 0; n8 < 8; ++n8) {
        accA[n8].x = __expf(accA[n8].x - gA0); sA0 += accA[n8].x;
        accA[n8].y = __expf(accA[n8].y - gA1); sA1 += accA[n8].y;
        accA[n8].z = __expf(accA[n8].z - gA2); sA2 += accA[n8].z;
        accA[n8].w = __expf(accA[n8].w - gA3); sA3 += accA[n8].w;
        accB[n8].x = __expf(accB[n8].x - gB0); sB0 += accB[n8].x;
        accB[n8].y = __expf(accB[n8].y - gB1); sB1 += accB[n8].y;
        accB[n8].z = __expf(accB[n8].z - gB2); sB2 += accB[n8].z;
        accB[n8].w = __expf(accB[n8].w - gB3); sB3 += accB[n8].w;
    }
    #pragma unroll
    for (int off = 8; off; off >>= 1) {
        sA0 += __shfl_xor(sA0, off); sA1 += __shfl_xor(sA1, off);
        sA2 += __shfl_xor(sA2, off); sA3 += __shfl_xor(sA3, off);
        sB0 += __shfl_xor(sB0, off); sB1 += __shfl_xor(sB1, off);
        sB2 += __shfl_xor(sB2, off); sB3 += __shfl_xor(sB3, off);
    }
    if (c16 == 0) {
        redsum[w][g * 4 + 0] = sA0;  redsum[w][g * 4 + 1] = sA1;
        redsum[w][g * 4 + 2] = sA2;  redsum[w][g * 4 + 3] = sA3;
        redsum[w][16 + g * 4 + 0] = sB0;  redsum[w][16 + g * 4 + 1] = sB1;
        redsum[w][16 + g * 4 + 2] = sB2;  redsum[w][16 + g * 4 + 3] = sB3;
    }
    __syncthreads();
#define GSUM(r) (redsum[0][r] + redsum[1][r] + redsum[2][r] + redsum[3][r])
    float iA0 = 1.0f / GSUM(g * 4 + 0), iA1 = 1.0f / GSUM(g * 4 + 1);
    float iA2 = 1.0f / GSUM(g * 4 + 2), iA3 = 1.0f / GSUM(g * 4 + 3);
    float iB0 = 1.0f / GSUM(16 + g * 4 + 0), iB1 = 1.0f / GSUM(16 + g * 4 + 1);
    float iB2 = 1.0f / GSUM(16 + g * 4 + 2), iB3 = 1.0f / GSUM(16 + g * 4 + 3);
#undef GSUM

    // ---- store: out[(vbase+s*16+g*4+j)*512 + n*16 + c16] ----
    #pragma unroll
    for (int n8 = 0; n8 < 8; ++n8) {
        int n = w * 8 + n8;
        float* opA = out + (size_t)(vbase + g * 4) * 512 + n * 16 + c16;
        __builtin_nontemporal_store(accA[n8].x * iA0, opA);
        __builtin_nontemporal_store(accA[n8].y * iA1, opA + 512);
        __builtin_nontemporal_store(accA[n8].z * iA2, opA + 1024);
        __builtin_nontemporal_store(accA[n8].w * iA3, opA + 1536);
        float* opB = opA + 16 * 512;
        __builtin_nontemporal_store(accB[n8].x * iB0, opB);
        __builtin_nontemporal_store(accB[n8].y * iB1, opB + 512);
        __builtin_nontemporal_store(accB[n8].z * iB2, opB + 1024);
        __builtin_nontemporal_store(accB[n8].w * iB3, opB + 1536);
    }
}

extern "C" void kernel_launch(void* const* d_in, const int* in_sizes, int n_in,
                              void* d_out, int out_size, void* d_ws, size_t ws_size,
                              hipStream_t stream) {
    (void)n_in; (void)out_size; (void)ws_size;
    const float* vp  = (const float*)d_in[0];
    const int*   nb1 = (const int*)d_in[1];
    const int*   nb2 = (const int*)d_in[2];
    const float* wv1 = (const float*)d_in[3];
    const float* bv1 = (const float*)d_in[4];
    const float* w1  = (const float*)d_in[5];
    const float* b1  = (const float*)d_in[6];
    const float* wv2 = (const float*)d_in[7];
    const float* bv2 = (const float*)d_in[8];
    const float* w2  = (const float*)d_in[9];
    const float* b2  = (const float*)d_in[10];
    const float* wfc = (const float*)d_in[11];
    const float* bfc = (const float*)d_in[12];
    float* out = (float*)d_out;
    const int V = in_sizes[0];

    float* ws = (float*)d_ws;
    size_t off = 0;
    float* h    = ws + off; off += (size_t)V;
    float* f1   = ws + off; off += (size_t)V * 32;
    float* h2   = ws + off; off += (size_t)V * 32;
    float* f2   = ws + off; off += (size_t)V * 64;
    float* w2t  = ws + off; off += 3 * 32 * 64;
    short* wBh  = (short*)(ws + off); off += 32768 / 2;   // 32768 shorts
    short* wBm  = (short*)(ws + off); off += 32768 / 2;
    short* wBl  = (short*)(ws + off); off += 32768 / 2;

    k_prep<<<(32768 + 6144 + 255) / 256, 256, 0, stream>>>(wfc, w2, wBh, wBm, wBl, w2t);
    kA<<<(V * 32 + 255) / 256, 256, 0, stream>>>(vp, nb1, wv1, bv1, h, V);
    kB<<<(V * 32 + 255) / 256, 256, 0, stream>>>(h, w1, b1, f1, V);
    kC<<<(V + 3) / 4, 256, 0, stream>>>(f1, nb2, wv2, bv2, h2, V);
    kD<<<(V + 31) / 32, 256, 0, stream>>>(h2, w2t, b2, f2, V);
    kE<<<V / 32, 256, 0, stream>>>(f2, wBh, wBm, wBl, bfc, out, V);
}

// Round 11
// 422.455 us; speedup vs baseline: 1.0594x; 1.0594x over previous
//
#include <hip/hip_runtime.h>

// ---------------------------------------------------------------------------
// Pipeline:
//  k_prep : w2[64,32,3] -> w2t[3,32,64]; wfc[512,64] -> wB{h,m,l} bf16
//  kA     : h[v] = mean_j relu(conv3_j(vp[nb1[v,:]]))               [V]
//  kB     : h3[v] = (h[v-1], h[v], h[v+1], 0)                       [V,4]
//  kC     : h2[v,c] = mean_j relu(conv3_j( f1(nb2[v,j], c) ))       [V,32]
//           where f1(x,c) = h3[x].x*w1[c,0]+h3[x].y*w1[c,1]+h3[x].z*w1[c,2]+b1[c]
//           (f1 is SYNTHESIZED in-register, never materialized)
//  kD     : f2[v,o] = sum_{k,c} h2[v-1+k,c]*w2t[k,c,o] + b2[o]      [V,64]
//  kE     : out[v,:] = softmax(f2[v,:] @ wfc^T + bfc)               [V,512]
//
// R14 changes:
//  - R13's float4-lane kC REVERTED: it cut per-wave outstanding loads
//    32->4 on a latency-bound gather (-32us regression). MLP is the
//    currency, not instruction count.
//  - kC root cause: 3.2M random 128B-row touches of a 12.8MB f1 -- too
//    big for a 4MB XCD L2, every row is an L3 round trip (~410MB of
//    L2-miss traffic). Three load-shape variants all ~100-110us.
//  - Fix: DON'T GATHER f1. f1[x,c] is a linear function of 3 h values;
//    gather h3[x]=(h[x-1],h[x],h[x+1],0) instead: 1.6MB, L2-RESIDENT,
//    same-address-across-half -> coalesced broadcast loads. Synthesize
//    x[j] with kB's exact fmaf chain -> bit-identical, absmax unchanged.
//    kB now just builds h3; f1 (12.8MB write+read) is gone.
// ---------------------------------------------------------------------------

typedef short bf16x8 __attribute__((ext_vector_type(8)));
typedef float f32x4 __attribute__((ext_vector_type(4)));

__device__ inline unsigned short f2bf(float x) {
    unsigned u = __float_as_uint(x);
    unsigned r = (u + 0x7FFFu + ((u >> 16) & 1u)) >> 16;
    return (unsigned short)r;
}
__device__ inline float bf2f(unsigned short b) {
    return __uint_as_float(((unsigned)b) << 16);
}

// k_prep: w2 transpose + wfc -> 3-way bf16 split in B-fragment order.
__global__ __launch_bounds__(256) void k_prep(const float* __restrict__ wfc,
                                              const float* __restrict__ w2,
                                              short* __restrict__ wBh,
                                              short* __restrict__ wBm,
                                              short* __restrict__ wBl,
                                              float* __restrict__ w2t) {
    int t = blockIdx.x * 256 + threadIdx.x;
    if (t < 32768) {
        int j = t & 7;
        int l = (t >> 3) & 63;
        int s = (t >> 9) & 1;
        int n = t >> 10;
        int col = n * 16 + (l & 15);
        int k = s * 32 + (l >> 4) * 8 + j;
        float v = wfc[col * 64 + k];
        unsigned short h = f2bf(v);
        float r1 = v - bf2f(h);
        unsigned short m = f2bf(r1);
        float r2 = r1 - bf2f(m);
        wBh[t] = (short)h;
        wBm[t] = (short)m;
        wBl[t] = (short)f2bf(r2);
    } else if (t < 32768 + 6144) {
        int i = t - 32768;
        int o = i / 96;
        int r = i - o * 96;
        int c = r / 3;
        int k = r - c * 3;
        w2t[(k * 32 + c) * 64 + o] = w2[i];
    }
}

// conv1 over neighbor axis: one 32-lane segment per vertex
__global__ __launch_bounds__(256) void kA(const float* __restrict__ vp,
                                          const int* __restrict__ nb1,
                                          const float* __restrict__ wv1,
                                          const float* __restrict__ bv1,
                                          float* __restrict__ h, int V) {
    int t = blockIdx.x * 256 + threadIdx.x;
    int v = t >> 5;
    int j = t & 31;
    if (v >= V) return;
    float g = vp[nb1[v * 32 + j]];
    float gm = __shfl_up(g, 1, 32);
    if (j == 0) gm = 0.0f;
    float gp = __shfl_down(g, 1, 32);
    if (j == 31) gp = 0.0f;
    float c = wv1[0] * gm + wv1[1] * g + wv1[2] * gp + bv1[0];
    c = fmaxf(c, 0.0f);
    #pragma unroll
    for (int off = 16; off; off >>= 1) c += __shfl_xor(c, off, 32);
    if (j == 0) h[v] = c * (1.0f / 32.0f);
}

// h3 builder: h3[v] = (h[v-1], h[v], h[v+1], 0) -- 1.6MB, L2-resident
__global__ __launch_bounds__(256) void kB(const float* __restrict__ h,
                                          float* __restrict__ h3, int V) {
    int v = blockIdx.x * 256 + threadIdx.x;
    if (v >= V) return;
    float hm = (v > 0) ? h[v - 1] : 0.0f;
    float h0 = h[v];
    float hp = (v + 1 < V) ? h[v + 1] : 0.0f;
    *(float4*)(h3 + (size_t)v * 4) = make_float4(hm, h0, hp, 0.0f);
}

// conv2: 2 vertices per wave (one per 32-lane half), lane = channel.
// Per j: ONE h3[idx] float4 load (same addr across the half -> coalesced
// broadcast, L2-hit) + 3 FMA synthesize x[j] = f1[idx][c] (kB's exact
// fmaf chain -> bit-identical). 32 independent loads in flight per lane.
__global__ __launch_bounds__(256) void kC(const float* __restrict__ h3,
                                          const int* __restrict__ nb2,
                                          const float* __restrict__ w1,
                                          const float* __restrict__ b1,
                                          const float* __restrict__ wv2,
                                          const float* __restrict__ bv2,
                                          float* __restrict__ h2, int V) {
    int t = threadIdx.x;
    int v = blockIdx.x * 8 + (t >> 5);   // one vertex per 32-lane half-wave
    int c = t & 31;                      // channel
    if (v >= V) return;
    int nbl = nb2[(size_t)v * 32 + c];   // lane c holds nb[c]
    float u0 = w1[c * 3 + 0], u1 = w1[c * 3 + 1], u2 = w1[c * 3 + 2];
    float bc = b1[c];

    float x[32];
    #pragma unroll
    for (int j = 0; j < 32; ++j) {
        int idx = __shfl(nbl, j, 32);
        float4 hh = *(const float4*)(h3 + (size_t)idx * 4);
        x[j] = fmaf(hh.x, u0, fmaf(hh.y, u1, fmaf(hh.z, u2, bc)));
    }

    float w0 = wv2[0], w1_ = wv2[1], w2_ = wv2[2], b = bv2[0];
    float s = 0.0f;
    #pragma unroll
    for (int j = 0; j < 32; ++j) {
        float pv = (j > 0)  ? x[j - 1] : 0.0f;
        float nx = (j < 31) ? x[j + 1] : 0.0f;
        float cv = fmaf(w0, pv, fmaf(w1_, x[j], fmaf(w2_, nx, b)));
        s += fmaxf(cv, 0.0f);
    }
    h2[(size_t)v * 32 + c] = s * (1.0f / 32.0f);
}

// f2 einsum: 256 threads / 32 vertices per block, h2 halo tile in LDS.
__global__ __launch_bounds__(256) void kD(const float* __restrict__ h2,
                                          const float* __restrict__ w2t,
                                          const float* __restrict__ b2,
                                          float* __restrict__ f2, int V) {
    __shared__ float tile[34 * 32];     // 4.25 KB, rows v0-1 .. v0+32
    int t = threadIdx.x;
    int v0 = blockIdx.x * 32;

    for (int i = t; i < 272; i += 256) {
        int r = i >> 3;
        int s = i & 7;
        int v = v0 - 1 + r;
        float4 val = make_float4(0.f, 0.f, 0.f, 0.f);
        if (v >= 0 && v < V)
            val = *(const float4*)(h2 + (size_t)v * 32 + s * 4);
        *(float4*)(tile + r * 32 + s * 4) = val;
    }
    __syncthreads();

    int o = t & 63;
    int w = t >> 6;
    int vb = w * 8;
    float bo = b2[o];
    float acc[8];
    #pragma unroll
    for (int m = 0; m < 8; ++m) acc[m] = bo;

    #pragma unroll
    for (int c4 = 0; c4 < 8; ++c4) {
        float4 hv[10];
        #pragma unroll
        for (int r = 0; r < 10; ++r)
            hv[r] = *(const float4*)(tile + (vb + r) * 32 + c4 * 4);
        #pragma unroll
        for (int k = 0; k < 3; ++k) {
            #pragma unroll
            for (int cc = 0; cc < 4; ++cc) {
                int c = c4 * 4 + cc;
                float wv = w2t[(k * 32 + c) * 64 + o];
                #pragma unroll
                for (int m = 0; m < 8; ++m) {
                    float hval = (cc == 0) ? hv[m + k].x :
                                 (cc == 1) ? hv[m + k].y :
                                 (cc == 2) ? hv[m + k].z : hv[m + k].w;
                    acc[m] = fmaf(hval, wv, acc[m]);
                }
            }
        }
    }
    #pragma unroll
    for (int m = 0; m < 8; ++m) {
        int v = v0 + vb + m;
        if (v < V) f2[(size_t)v * 64 + o] = acc[m];
    }
}

// fc + softmax on the MATRIX pipe. 256 thr / 32 vertices / block.
// Two A-row-sets per wave; each B frag load feeds 24 MFMAs.
// C/D: col=lane&15, row=(lane>>4)*4+reg.
__global__ __launch_bounds__(256) void kE(const float* __restrict__ f2,
                                          const short* __restrict__ wBh,
                                          const short* __restrict__ wBm,
                                          const short* __restrict__ wBl,
                                          const float* __restrict__ bfc,
                                          float* __restrict__ out, int V) {
    __shared__ float redmax[4][32];
    __shared__ float redsum[4][32];
    int t = threadIdx.x;
    int w = t >> 6;          // wave 0..3
    int l = t & 63;          // lane
    int c16 = l & 15;
    int g = l >> 4;          // K-group / row-group
    int vbase = blockIdx.x * 32;   // V % 32 == 0

    // ---- A fragments: two row-sets, 3-way bf16 split ----
    bf16x8 ah0[2], am0[2], al0[2], ah1[2], am1[2], al1[2];
#define SPLIT(AH, AM, AL, idx, x) { \
        float xx = (x); \
        unsigned short h_ = f2bf(xx); \
        float r1_ = xx - bf2f(h_); \
        unsigned short m_ = f2bf(r1_); \
        float r2_ = r1_ - bf2f(m_); \
        AH[idx] = (short)h_; AM[idx] = (short)m_; AL[idx] = (short)f2bf(r2_); }
    #pragma unroll
    for (int set = 0; set < 2; ++set) {
        const float* rowp = f2 + (size_t)(vbase + set * 16 + c16) * 64 + g * 8;
        float4 q0 = *(const float4*)(rowp);        // s=0, k=g*8..+3
        float4 q1 = *(const float4*)(rowp + 4);    // s=0, k=g*8+4..+7
        float4 q2 = *(const float4*)(rowp + 32);   // s=1
        float4 q3 = *(const float4*)(rowp + 36);
        SPLIT(ah0[set], am0[set], al0[set], 0, q0.x)
        SPLIT(ah0[set], am0[set], al0[set], 1, q0.y)
        SPLIT(ah0[set], am0[set], al0[set], 2, q0.z)
        SPLIT(ah0[set], am0[set], al0[set], 3, q0.w)
        SPLIT(ah0[set], am0[set], al0[set], 4, q1.x)
        SPLIT(ah0[set], am0[set], al0[set], 5, q1.y)
        SPLIT(ah0[set], am0[set], al0[set], 6, q1.z)
        SPLIT(ah0[set], am0[set], al0[set], 7, q1.w)
        SPLIT(ah1[set], am1[set], al1[set], 0, q2.x)
        SPLIT(ah1[set], am1[set], al1[set], 1, q2.y)
        SPLIT(ah1[set], am1[set], al1[set], 2, q2.z)
        SPLIT(ah1[set], am1[set], al1[set], 3, q2.w)
        SPLIT(ah1[set], am1[set], al1[set], 4, q3.x)
        SPLIT(ah1[set], am1[set], al1[set], 5, q3.y)
        SPLIT(ah1[set], am1[set], al1[set], 6, q3.z)
        SPLIT(ah1[set], am1[set], al1[set], 7, q3.w)
    }
#undef SPLIT

    // ---- MFMA: 8 N-tiles per wave, 2 K-steps, 6 products, 2 row-sets ----
    f32x4 accA[8], accB[8];
    const bf16x8* Bh = (const bf16x8*)wBh;
    const bf16x8* Bm = (const bf16x8*)wBm;
    const bf16x8* Bl = (const bf16x8*)wBl;
    #pragma unroll
    for (int n8 = 0; n8 < 8; ++n8) {
        int n = w * 8 + n8;
        bf16x8 bh0 = Bh[(n * 2 + 0) * 64 + l];
        bf16x8 bm0 = Bm[(n * 2 + 0) * 64 + l];
        bf16x8 bl0 = Bl[(n * 2 + 0) * 64 + l];
        bf16x8 bh1 = Bh[(n * 2 + 1) * 64 + l];
        bf16x8 bm1 = Bm[(n * 2 + 1) * 64 + l];
        bf16x8 bl1 = Bl[(n * 2 + 1) * 64 + l];
        float bn = bfc[n * 16 + c16];
        f32x4 cA = {0.f, 0.f, 0.f, 0.f};
        cA = __builtin_amdgcn_mfma_f32_16x16x32_bf16(ah0[0], bh0, cA, 0, 0, 0);
        cA = __builtin_amdgcn_mfma_f32_16x16x32_bf16(ah0[0], bm0, cA, 0, 0, 0);
        cA = __builtin_amdgcn_mfma_f32_16x16x32_bf16(am0[0], bh0, cA, 0, 0, 0);
        cA = __builtin_amdgcn_mfma_f32_16x16x32_bf16(ah0[0], bl0, cA, 0, 0, 0);
        cA = __builtin_amdgcn_mfma_f32_16x16x32_bf16(am0[0], bm0, cA, 0, 0, 0);
        cA = __builtin_amdgcn_mfma_f32_16x16x32_bf16(al0[0], bh0, cA, 0, 0, 0);
        cA = __builtin_amdgcn_mfma_f32_16x16x32_bf16(ah1[0], bh1, cA, 0, 0, 0);
        cA = __builtin_amdgcn_mfma_f32_16x16x32_bf16(ah1[0], bm1, cA, 0, 0, 0);
        cA = __builtin_amdgcn_mfma_f32_16x16x32_bf16(am1[0], bh1, cA, 0, 0, 0);
        cA = __builtin_amdgcn_mfma_f32_16x16x32_bf16(ah1[0], bl1, cA, 0, 0, 0);
        cA = __builtin_amdgcn_mfma_f32_16x16x32_bf16(am1[0], bm1, cA, 0, 0, 0);
        cA = __builtin_amdgcn_mfma_f32_16x16x32_bf16(al1[0], bh1, cA, 0, 0, 0);
        cA.x += bn; cA.y += bn; cA.z += bn; cA.w += bn;
        accA[n8] = cA;
        f32x4 cB = {0.f, 0.f, 0.f, 0.f};
        cB = __builtin_amdgcn_mfma_f32_16x16x32_bf16(ah0[1], bh0, cB, 0, 0, 0);
        cB = __builtin_amdgcn_mfma_f32_16x16x32_bf16(ah0[1], bm0, cB, 0, 0, 0);
        cB = __builtin_amdgcn_mfma_f32_16x16x32_bf16(am0[1], bh0, cB, 0, 0, 0);
        cB = __builtin_amdgcn_mfma_f32_16x16x32_bf16(ah0[1], bl0, cB, 0, 0, 0);
        cB = __builtin_amdgcn_mfma_f32_16x16x32_bf16(am0[1], bm0, cB, 0, 0, 0);
        cB = __builtin_amdgcn_mfma_f32_16x16x32_bf16(al0[1], bh0, cB, 0, 0, 0);
        cB = __builtin_amdgcn_mfma_f32_16x16x32_bf16(ah1[1], bh1, cB, 0, 0, 0);
        cB = __builtin_amdgcn_mfma_f32_16x16x32_bf16(ah1[1], bm1, cB, 0, 0, 0);
        cB = __builtin_amdgcn_mfma_f32_16x16x32_bf16(am1[1], bh1, cB, 0, 0, 0);
        cB = __builtin_amdgcn_mfma_f32_16x16x32_bf16(ah1[1], bl1, cB, 0, 0, 0);
        cB = __builtin_amdgcn_mfma_f32_16x16x32_bf16(am1[1], bm1, cB, 0, 0, 0);
        cB = __builtin_amdgcn_mfma_f32_16x16x32_bf16(al1[1], bh1, cB, 0, 0, 0);
        cB.x += bn; cB.y += bn; cB.z += bn; cB.w += bn;
        accB[n8] = cB;
    }

    // ---- softmax: per reg j, set s: row = s*16 + g*4 + j ----
    float mA0 = -1e30f, mA1 = -1e30f, mA2 = -1e30f, mA3 = -1e30f;
    float mB0 = -1e30f, mB1 = -1e30f, mB2 = -1e30f, mB3 = -1e30f;
    #pragma unroll
    for (int n8 = 0; n8 < 8; ++n8) {
        mA0 = fmaxf(mA0, accA[n8].x); mA1 = fmaxf(mA1, accA[n8].y);
        mA2 = fmaxf(mA2, accA[n8].z); mA3 = fmaxf(mA3, accA[n8].w);
        mB0 = fmaxf(mB0, accB[n8].x); mB1 = fmaxf(mB1, accB[n8].y);
        mB2 = fmaxf(mB2, accB[n8].z); mB3 = fmaxf(mB3, accB[n8].w);
    }
    #pragma unroll
    for (int off = 8; off; off >>= 1) {
        mA0 = fmaxf(mA0, __shfl_xor(mA0, off));
        mA1 = fmaxf(mA1, __shfl_xor(mA1, off));
        mA2 = fmaxf(mA2, __shfl_xor(mA2, off));
        mA3 = fmaxf(mA3, __shfl_xor(mA3, off));
        mB0 = fmaxf(mB0, __shfl_xor(mB0, off));
        mB1 = fmaxf(mB1, __shfl_xor(mB1, off));
        mB2 = fmaxf(mB2, __shfl_xor(mB2, off));
        mB3 = fmaxf(mB3, __shfl_xor(mB3, off));
    }
    if (c16 == 0) {
        redmax[w][g * 4 + 0] = mA0;  redmax[w][g * 4 + 1] = mA1;
        redmax[w][g * 4 + 2] = mA2;  redmax[w][g * 4 + 3] = mA3;
        redmax[w][16 + g * 4 + 0] = mB0;  redmax[w][16 + g * 4 + 1] = mB1;
        redmax[w][16 + g * 4 + 2] = mB2;  redmax[w][16 + g * 4 + 3] = mB3;
    }
    __syncthreads();
#define GMAX(r) fmaxf(fmaxf(redmax[0][r], redmax[1][r]), \
                      fmaxf(redmax[2][r], redmax[3][r]))
    float gA0 = GMAX(g * 4 + 0), gA1 = GMAX(g * 4 + 1);
    float gA2 = GMAX(g * 4 + 2), gA3 = GMAX(g * 4 + 3);
    float gB0 = GMAX(16 + g * 4 + 0), gB1 = GMAX(16 + g * 4 + 1);
    float gB2 = GMAX(16 + g * 4 + 2), gB3 = GMAX(16 + g * 4 + 3);
#undef GMAX

    float sA0 = 0.f, sA1 = 0.f, sA2 = 0.f, sA3 = 0.f;
    float sB0 = 0.f, sB1 = 0.f, sB2 = 0.f, sB3 = 0.f;
    #pragma unroll
    for (int n8 = 0; n8 < 8; ++n8) {
        accA[n8].x = __expf(accA[n8].x - gA0); sA0 += accA[n8].x;
        accA[n8].y = __expf(accA[n8].y - gA1); sA1 += accA[n8].y;
        accA[n8].z = __expf(accA[n8].z - gA2); sA2 += accA[n8].z;
        accA[n8].w = __expf(accA[n8].w - gA3); sA3 += accA[n8].w;
        accB[n8].x = __expf(accB[n8].x - gB0); sB0 += accB[n8].x;
        accB[n8].y = __expf(accB[n8].y - gB1); sB1 += accB[n8].y;
        accB[n8].z = __expf(accB[n8].z - gB2); sB2 += accB[n8].z;
        accB[n8].w = __expf(accB[n8].w - gB3); sB3 += accB[n8].w;
    }
    #pragma unroll
    for (int off = 8; off; off >>= 1) {
        sA0 += __shfl_xor(sA0, off); sA1 += __shfl_xor(sA1, off);
        sA2 += __shfl_xor(sA2, off); sA3 += __shfl_xor(sA3, off);
        sB0 += __shfl_xor(sB0, off); sB1 += __shfl_xor(sB1, off);
        sB2 += __shfl_xor(sB2, off); sB3 += __shfl_xor(sB3, off);
    }
    if (c16 == 0) {
        redsum[w][g * 4 + 0] = sA0;  redsum[w][g * 4 + 1] = sA1;
        redsum[w][g * 4 + 2] = sA2;  redsum[w][g * 4 + 3] = sA3;
        redsum[w][16 + g * 4 + 0] = sB0;  redsum[w][16 + g * 4 + 1] = sB1;
        redsum[w][16 + g * 4 + 2] = sB2;  redsum[w][16 + g * 4 + 3] = sB3;
    }
    __syncthreads();
#define GSUM(r) (redsum[0][r] + redsum[1][r] + redsum[2][r] + redsum[3][r])
    float iA0 = 1.0f / GSUM(g * 4 + 0), iA1 = 1.0f / GSUM(g * 4 + 1);
    float iA2 = 1.0f / GSUM(g * 4 + 2), iA3 = 1.0f / GSUM(g * 4 + 3);
    float iB0 = 1.0f / GSUM(16 + g * 4 + 0), iB1 = 1.0f / GSUM(16 + g * 4 + 1);
    float iB2 = 1.0f / GSUM(16 + g * 4 + 2), iB3 = 1.0f / GSUM(16 + g * 4 + 3);
#undef GSUM

    // ---- store: out[(vbase+s*16+g*4+j)*512 + n*16 + c16] ----
    #pragma unroll
    for (int n8 = 0; n8 < 8; ++n8) {
        int n = w * 8 + n8;
        float* opA = out + (size_t)(vbase + g * 4) * 512 + n * 16 + c16;
        __builtin_nontemporal_store(accA[n8].x * iA0, opA);
        __builtin_nontemporal_store(accA[n8].y * iA1, opA + 512);
        __builtin_nontemporal_store(accA[n8].z * iA2, opA + 1024);
        __builtin_nontemporal_store(accA[n8].w * iA3, opA + 1536);
        float* opB = opA + 16 * 512;
        __builtin_nontemporal_store(accB[n8].x * iB0, opB);
        __builtin_nontemporal_store(accB[n8].y * iB1, opB + 512);
        __builtin_nontemporal_store(accB[n8].z * iB2, opB + 1024);
        __builtin_nontemporal_store(accB[n8].w * iB3, opB + 1536);
    }
}

extern "C" void kernel_launch(void* const* d_in, const int* in_sizes, int n_in,
                              void* d_out, int out_size, void* d_ws, size_t ws_size,
                              hipStream_t stream) {
    (void)n_in; (void)out_size; (void)ws_size;
    const float* vp  = (const float*)d_in[0];
    const int*   nb1 = (const int*)d_in[1];
    const int*   nb2 = (const int*)d_in[2];
    const float* wv1 = (const float*)d_in[3];
    const float* bv1 = (const float*)d_in[4];
    const float* w1  = (const float*)d_in[5];
    const float* b1  = (const float*)d_in[6];
    const float* wv2 = (const float*)d_in[7];
    const float* bv2 = (const float*)d_in[8];
    const float* w2  = (const float*)d_in[9];
    const float* b2  = (const float*)d_in[10];
    const float* wfc = (const float*)d_in[11];
    const float* bfc = (const float*)d_in[12];
    float* out = (float*)d_out;
    const int V = in_sizes[0];

    float* ws = (float*)d_ws;
    size_t off = 0;
    float* h    = ws + off; off += (size_t)V;
    float* h3   = ws + off; off += (size_t)V * 4;   // V%4==0 -> 16B aligned
    float* h2   = ws + off; off += (size_t)V * 32;
    float* f2   = ws + off; off += (size_t)V * 64;
    float* w2t  = ws + off; off += 3 * 32 * 64;
    short* wBh  = (short*)(ws + off); off += 32768 / 2;   // 32768 shorts
    short* wBm  = (short*)(ws + off); off += 32768 / 2;
    short* wBl  = (short*)(ws + off); off += 32768 / 2;

    k_prep<<<(32768 + 6144 + 255) / 256, 256, 0, stream>>>(wfc, w2, wBh, wBm, wBl, w2t);
    kA<<<(V * 32 + 255) / 256, 256, 0, stream>>>(vp, nb1, wv1, bv1, h, V);
    kB<<<(V + 255) / 256, 256, 0, stream>>>(h, h3, V);
    kC<<<(V + 7) / 8, 256, 0, stream>>>(h3, nb2, w1, b1, wv2, bv2, h2, V);
    kD<<<(V + 31) / 32, 256, 0, stream>>>(h2, w2t, b2, f2, V);
    kE<<<V / 32, 256, 0, stream>>>(f2, wBh, wBm, wBl, bfc, out, V);
}

// Round 12
// 386.503 us; speedup vs baseline: 1.1579x; 1.0930x over previous
//
#include <hip/hip_runtime.h>

// ---------------------------------------------------------------------------
// Pipeline:
//  k_prep : w2[64,32,3] -> w2t[3,32,64]; wfc[512,64] -> wB{h,m,l} bf16
//  kA     : h[v] = mean_j relu(conv3_j(vp[nb1[v,:]]))               [V]
//  kB     : h3[v] = (h[v-1], h[v], h[v+1], 0)                       [V,4]
//  kF     : FUSED kC+kD+kE per 32-vertex block:
//           ph1 gather h3[nb2[v,j]] for 34 halo rows -> LDS
//           ph2 h2[34][32] in LDS (f1 synthesized in-register)
//           ph3 kD einsum from LDS -> f2s[32][68] LDS (68: bank-conflict pad)
//           ph4 kE 3-way-bf16-split MFMA fc + softmax -> out
//           h2/f2 never touch global (~77MB saved); co-resident blocks sit
//           in different phases -> gather latency hides under MFMA (m114).
//
// R15: R9/R10/R11 bracketed kC as latency-bound with MLP the only lever
// (R10 cut MLP -> +32us; R9~R11 within 7us). Single-kernel reshaping
// plateaued at 415. The structural fix is cross-phase overlap: fuse.
// All fmaf chains bit-identical to R11 (absmax must stay 1.525879e-05).
// ---------------------------------------------------------------------------

typedef short bf16x8 __attribute__((ext_vector_type(8)));
typedef float f32x4 __attribute__((ext_vector_type(4)));

__device__ inline unsigned short f2bf(float x) {
    unsigned u = __float_as_uint(x);
    unsigned r = (u + 0x7FFFu + ((u >> 16) & 1u)) >> 16;
    return (unsigned short)r;
}
__device__ inline float bf2f(unsigned short b) {
    return __uint_as_float(((unsigned)b) << 16);
}

// k_prep: w2 transpose + wfc -> 3-way bf16 split in B-fragment order.
__global__ __launch_bounds__(256) void k_prep(const float* __restrict__ wfc,
                                              const float* __restrict__ w2,
                                              short* __restrict__ wBh,
                                              short* __restrict__ wBm,
                                              short* __restrict__ wBl,
                                              float* __restrict__ w2t) {
    int t = blockIdx.x * 256 + threadIdx.x;
    if (t < 32768) {
        int j = t & 7;
        int l = (t >> 3) & 63;
        int s = (t >> 9) & 1;
        int n = t >> 10;
        int col = n * 16 + (l & 15);
        int k = s * 32 + (l >> 4) * 8 + j;
        float v = wfc[col * 64 + k];
        unsigned short h = f2bf(v);
        float r1 = v - bf2f(h);
        unsigned short m = f2bf(r1);
        float r2 = r1 - bf2f(m);
        wBh[t] = (short)h;
        wBm[t] = (short)m;
        wBl[t] = (short)f2bf(r2);
    } else if (t < 32768 + 6144) {
        int i = t - 32768;
        int o = i / 96;
        int r = i - o * 96;
        int c = r / 3;
        int k = r - c * 3;
        w2t[(k * 32 + c) * 64 + o] = w2[i];
    }
}

// conv1 over neighbor axis: one 32-lane segment per vertex
__global__ __launch_bounds__(256) void kA(const float* __restrict__ vp,
                                          const int* __restrict__ nb1,
                                          const float* __restrict__ wv1,
                                          const float* __restrict__ bv1,
                                          float* __restrict__ h, int V) {
    int t = blockIdx.x * 256 + threadIdx.x;
    int v = t >> 5;
    int j = t & 31;
    if (v >= V) return;
    float g = vp[nb1[v * 32 + j]];
    float gm = __shfl_up(g, 1, 32);
    if (j == 0) gm = 0.0f;
    float gp = __shfl_down(g, 1, 32);
    if (j == 31) gp = 0.0f;
    float c = wv1[0] * gm + wv1[1] * g + wv1[2] * gp + bv1[0];
    c = fmaxf(c, 0.0f);
    #pragma unroll
    for (int off = 16; off; off >>= 1) c += __shfl_xor(c, off, 32);
    if (j == 0) h[v] = c * (1.0f / 32.0f);
}

// h3 builder: h3[v] = (h[v-1], h[v], h[v+1], 0) -- 1.6MB, L2-resident
__global__ __launch_bounds__(256) void kB(const float* __restrict__ h,
                                          float* __restrict__ h3, int V) {
    int v = blockIdx.x * 256 + threadIdx.x;
    if (v >= V) return;
    float hm = (v > 0) ? h[v - 1] : 0.0f;
    float h0 = h[v];
    float hp = (v + 1 < V) ? h[v + 1] : 0.0f;
    *(float4*)(h3 + (size_t)v * 4) = make_float4(hm, h0, hp, 0.0f);
}

// FUSED kC+kD+kE. One block = 32 vertices. V % 32 == 0.
__global__ __launch_bounds__(256) void kF(const float* __restrict__ h3,
                                          const int* __restrict__ nb2,
                                          const float* __restrict__ w1,
                                          const float* __restrict__ b1,
                                          const float* __restrict__ wv2,
                                          const float* __restrict__ bv2,
                                          const float* __restrict__ w2t,
                                          const float* __restrict__ b2,
                                          const short* __restrict__ wBh,
                                          const short* __restrict__ wBm,
                                          const short* __restrict__ wBl,
                                          const float* __restrict__ bfc,
                                          float* __restrict__ out, int V) {
    __shared__ float h3s[34 * 32 * 4];   // 17408 B; ph3+ aliased as f2s[32][68]
    __shared__ float h2s[34 * 32];       // 4352 B, rows v0-1 .. v0+32
    __shared__ float redmax[4][32];
    __shared__ float redsum[4][32];
    float* f2s = h3s;                    // alias (dead after ph2; barrier-fenced)

    int t = threadIdx.x;
    int vbase = blockIdx.x * 32;

    // ---- ph1: gather h3[nb2[v,j]] for 34 halo rows ----
    for (int i = t; i < 34 * 32; i += 256) {
        int r = i >> 5;                  // tile row, vertex v = vbase-1+r
        int j = i & 31;
        int v = vbase - 1 + r;
        float4 val = make_float4(0.f, 0.f, 0.f, 0.f);
        if (v >= 0 && v < V) {
            int idx = nb2[(size_t)v * 32 + j];
            val = *(const float4*)(h3 + (size_t)idx * 4);
        }
        *(float4*)(h3s + i * 4) = val;
    }
    __syncthreads();

    // ---- ph2: h2[r][c] = mean_j relu(conv3_j(f1_synth)) ----
    for (int i = t; i < 34 * 32; i += 256) {
        int r = i >> 5;
        int c = i & 31;
        int v = vbase - 1 + r;
        float res = 0.0f;
        if (v >= 0 && v < V) {
            float u0 = w1[c * 3 + 0], u1 = w1[c * 3 + 1], u2 = w1[c * 3 + 2];
            float bc = b1[c];
            float w0 = wv2[0], w1_ = wv2[1], w2_ = wv2[2], b = bv2[0];
            const float* base = h3s + r * 32 * 4;
            float4 hh = *(const float4*)(base);
            float xprev = 0.0f;
            float xcur = fmaf(hh.x, u0, fmaf(hh.y, u1, fmaf(hh.z, u2, bc)));
            float s = 0.0f;
            #pragma unroll
            for (int j = 0; j < 32; ++j) {
                float xnext = 0.0f;
                if (j < 31) {
                    float4 hn = *(const float4*)(base + (j + 1) * 4);
                    xnext = fmaf(hn.x, u0, fmaf(hn.y, u1, fmaf(hn.z, u2, bc)));
                }
                float cv = fmaf(w0, xprev, fmaf(w1_, xcur, fmaf(w2_, xnext, b)));
                s += fmaxf(cv, 0.0f);
                xprev = xcur;
                xcur = xnext;
            }
            res = s * (1.0f / 32.0f);
        }
        h2s[r * 32 + c] = res;
    }
    __syncthreads();

    // ---- ph3: kD einsum from h2s -> f2s[32][68] (LDS) ----
    {
        int o = t & 63;
        int w = t >> 6;
        int vb = w * 8;
        float bo = b2[o];
        float acc[8];
        #pragma unroll
        for (int m = 0; m < 8; ++m) acc[m] = bo;

        #pragma unroll
        for (int c4 = 0; c4 < 8; ++c4) {
            float4 hv[10];
            #pragma unroll
            for (int r = 0; r < 10; ++r)
                hv[r] = *(const float4*)(h2s + (vb + r) * 32 + c4 * 4);
            #pragma unroll
            for (int k = 0; k < 3; ++k) {
                #pragma unroll
                for (int cc = 0; cc < 4; ++cc) {
                    int c = c4 * 4 + cc;
                    float wv = w2t[(k * 32 + c) * 64 + o];
                    #pragma unroll
                    for (int m = 0; m < 8; ++m) {
                        float hval = (cc == 0) ? hv[m + k].x :
                                     (cc == 1) ? hv[m + k].y :
                                     (cc == 2) ? hv[m + k].z : hv[m + k].w;
                        acc[m] = fmaf(hval, wv, acc[m]);
                    }
                }
            }
        }
        __syncthreads();   // h3s reads (ph2) done everywhere; safe to alias
        #pragma unroll
        for (int m = 0; m < 8; ++m)
            f2s[(vb + m) * 68 + o] = acc[m];
    }
    __syncthreads();

    // ---- ph4: kE MFMA fc + softmax ----
    int w = t >> 6;          // wave 0..3
    int l = t & 63;          // lane
    int c16 = l & 15;
    int g = l >> 4;          // K-group / row-group

    bf16x8 ah0[2], am0[2], al0[2], ah1[2], am1[2], al1[2];
#define SPLIT(AH, AM, AL, idx, x) { \
        float xx = (x); \
        unsigned short h_ = f2bf(xx); \
        float r1_ = xx - bf2f(h_); \
        unsigned short m_ = f2bf(r1_); \
        float r2_ = r1_ - bf2f(m_); \
        AH[idx] = (short)h_; AM[idx] = (short)m_; AL[idx] = (short)f2bf(r2_); }
    #pragma unroll
    for (int set = 0; set < 2; ++set) {
        const float* rowp = f2s + (set * 16 + c16) * 68 + g * 8;
        float4 q0 = *(const float4*)(rowp);        // s=0, k=g*8..+3
        float4 q1 = *(const float4*)(rowp + 4);    // s=0, k=g*8+4..+7
        float4 q2 = *(const float4*)(rowp + 32);   // s=1
        float4 q3 = *(const float4*)(rowp + 36);
        SPLIT(ah0[set], am0[set], al0[set], 0, q0.x)
        SPLIT(ah0[set], am0[set], al0[set], 1, q0.y)
        SPLIT(ah0[set], am0[set], al0[set], 2, q0.z)
        SPLIT(ah0[set], am0[set], al0[set], 3, q0.w)
        SPLIT(ah0[set], am0[set], al0[set], 4, q1.x)
        SPLIT(ah0[set], am0[set], al0[set], 5, q1.y)
        SPLIT(ah0[set], am0[set], al0[set], 6, q1.z)
        SPLIT(ah0[set], am0[set], al0[set], 7, q1.w)
        SPLIT(ah1[set], am1[set], al1[set], 0, q2.x)
        SPLIT(ah1[set], am1[set], al1[set], 1, q2.y)
        SPLIT(ah1[set], am1[set], al1[set], 2, q2.z)
        SPLIT(ah1[set], am1[set], al1[set], 3, q2.w)
        SPLIT(ah1[set], am1[set], al1[set], 4, q3.x)
        SPLIT(ah1[set], am1[set], al1[set], 5, q3.y)
        SPLIT(ah1[set], am1[set], al1[set], 6, q3.z)
        SPLIT(ah1[set], am1[set], al1[set], 7, q3.w)
    }
#undef SPLIT

    f32x4 accA[8], accB[8];
    const bf16x8* Bh = (const bf16x8*)wBh;
    const bf16x8* Bm = (const bf16x8*)wBm;
    const bf16x8* Bl = (const bf16x8*)wBl;
    #pragma unroll
    for (int n8 = 0; n8 < 8; ++n8) {
        int n = w * 8 + n8;
        bf16x8 bh0 = Bh[(n * 2 + 0) * 64 + l];
        bf16x8 bm0 = Bm[(n * 2 + 0) * 64 + l];
        bf16x8 bl0 = Bl[(n * 2 + 0) * 64 + l];
        bf16x8 bh1 = Bh[(n * 2 + 1) * 64 + l];
        bf16x8 bm1 = Bm[(n * 2 + 1) * 64 + l];
        bf16x8 bl1 = Bl[(n * 2 + 1) * 64 + l];
        float bn = bfc[n * 16 + c16];
        f32x4 cA = {0.f, 0.f, 0.f, 0.f};
        cA = __builtin_amdgcn_mfma_f32_16x16x32_bf16(ah0[0], bh0, cA, 0, 0, 0);
        cA = __builtin_amdgcn_mfma_f32_16x16x32_bf16(ah0[0], bm0, cA, 0, 0, 0);
        cA = __builtin_amdgcn_mfma_f32_16x16x32_bf16(am0[0], bh0, cA, 0, 0, 0);
        cA = __builtin_amdgcn_mfma_f32_16x16x32_bf16(ah0[0], bl0, cA, 0, 0, 0);
        cA = __builtin_amdgcn_mfma_f32_16x16x32_bf16(am0[0], bm0, cA, 0, 0, 0);
        cA = __builtin_amdgcn_mfma_f32_16x16x32_bf16(al0[0], bh0, cA, 0, 0, 0);
        cA = __builtin_amdgcn_mfma_f32_16x16x32_bf16(ah1[0], bh1, cA, 0, 0, 0);
        cA = __builtin_amdgcn_mfma_f32_16x16x32_bf16(ah1[0], bm1, cA, 0, 0, 0);
        cA = __builtin_amdgcn_mfma_f32_16x16x32_bf16(am1[0], bh1, cA, 0, 0, 0);
        cA = __builtin_amdgcn_mfma_f32_16x16x32_bf16(ah1[0], bl1, cA, 0, 0, 0);
        cA = __builtin_amdgcn_mfma_f32_16x16x32_bf16(am1[0], bm1, cA, 0, 0, 0);
        cA = __builtin_amdgcn_mfma_f32_16x16x32_bf16(al1[0], bh1, cA, 0, 0, 0);
        cA.x += bn; cA.y += bn; cA.z += bn; cA.w += bn;
        accA[n8] = cA;
        f32x4 cB = {0.f, 0.f, 0.f, 0.f};
        cB = __builtin_amdgcn_mfma_f32_16x16x32_bf16(ah0[1], bh0, cB, 0, 0, 0);
        cB = __builtin_amdgcn_mfma_f32_16x16x32_bf16(ah0[1], bm0, cB, 0, 0, 0);
        cB = __builtin_amdgcn_mfma_f32_16x16x32_bf16(am0[1], bh0, cB, 0, 0, 0);
        cB = __builtin_amdgcn_mfma_f32_16x16x32_bf16(ah0[1], bl0, cB, 0, 0, 0);
        cB = __builtin_amdgcn_mfma_f32_16x16x32_bf16(am0[1], bm0, cB, 0, 0, 0);
        cB = __builtin_amdgcn_mfma_f32_16x16x32_bf16(al0[1], bh0, cB, 0, 0, 0);
        cB = __builtin_amdgcn_mfma_f32_16x16x32_bf16(ah1[1], bh1, cB, 0, 0, 0);
        cB = __builtin_amdgcn_mfma_f32_16x16x32_bf16(ah1[1], bm1, cB, 0, 0, 0);
        cB = __builtin_amdgcn_mfma_f32_16x16x32_bf16(am1[1], bh1, cB, 0, 0, 0);
        cB = __builtin_amdgcn_mfma_f32_16x16x32_bf16(ah1[1], bl1, cB, 0, 0, 0);
        cB = __builtin_amdgcn_mfma_f32_16x16x32_bf16(am1[1], bm1, cB, 0, 0, 0);
        cB = __builtin_amdgcn_mfma_f32_16x16x32_bf16(al1[1], bh1, cB, 0, 0, 0);
        cB.x += bn; cB.y += bn; cB.z += bn; cB.w += bn;
        accB[n8] = cB;
    }

    // ---- softmax ----
    float mA0 = -1e30f, mA1 = -1e30f, mA2 = -1e30f, mA3 = -1e30f;
    float mB0 = -1e30f, mB1 = -1e30f, mB2 = -1e30f, mB3 = -1e30f;
    #pragma unroll
    for (int n8 = 0; n8 < 8; ++n8) {
        mA0 = fmaxf(mA0, accA[n8].x); mA1 = fmaxf(mA1, accA[n8].y);
        mA2 = fmaxf(mA2, accA[n8].z); mA3 = fmaxf(mA3, accA[n8].w);
        mB0 = fmaxf(mB0, accB[n8].x); mB1 = fmaxf(mB1, accB[n8].y);
        mB2 = fmaxf(mB2, accB[n8].z); mB3 = fmaxf(mB3, accB[n8].w);
    }
    #pragma unroll
    for (int off = 8; off; off >>= 1) {
        mA0 = fmaxf(mA0, __shfl_xor(mA0, off));
        mA1 = fmaxf(mA1, __shfl_xor(mA1, off));
        mA2 = fmaxf(mA2, __shfl_xor(mA2, off));
        mA3 = fmaxf(mA3, __shfl_xor(mA3, off));
        mB0 = fmaxf(mB0, __shfl_xor(mB0, off));
        mB1 = fmaxf(mB1, __shfl_xor(mB1, off));
        mB2 = fmaxf(mB2, __shfl_xor(mB2, off));
        mB3 = fmaxf(mB3, __shfl_xor(mB3, off));
    }
    if (c16 == 0) {
        redmax[w][g * 4 + 0] = mA0;  redmax[w][g * 4 + 1] = mA1;
        redmax[w][g * 4 + 2] = mA2;  redmax[w][g * 4 + 3] = mA3;
        redmax[w][16 + g * 4 + 0] = mB0;  redmax[w][16 + g * 4 + 1] = mB1;
        redmax[w][16 + g * 4 + 2] = mB2;  redmax[w][16 + g * 4 + 3] = mB3;
    }
    __syncthreads();
#define GMAX(r) fmaxf(fmaxf(redmax[0][r], redmax[1][r]), \
                      fmaxf(redmax[2][r], redmax[3][r]))
    float gA0 = GMAX(g * 4 + 0), gA1 = GMAX(g * 4 + 1);
    float gA2 = GMAX(g * 4 + 2), gA3 = GMAX(g * 4 + 3);
    float gB0 = GMAX(16 + g * 4 + 0), gB1 = GMAX(16 + g * 4 + 1);
    float gB2 = GMAX(16 + g * 4 + 2), gB3 = GMAX(16 + g * 4 + 3);
#undef GMAX

    float sA0 = 0.f, sA1 = 0.f, sA2 = 0.f, sA3 = 0.f;
    float sB0 = 0.f, sB1 = 0.f, sB2 = 0.f, sB3 = 0.f;
    #pragma unroll
    for (int n8 = 0; n8 < 8; ++n8) {
        accA[n8].x = __expf(accA[n8].x - gA0); sA0 += accA[n8].x;
        accA[n8].y = __expf(accA[n8].y - gA1); sA1 += accA[n8].y;
        accA[n8].z = __expf(accA[n8].z - gA2); sA2 += accA[n8].z;
        accA[n8].w = __expf(accA[n8].w - gA3); sA3 += accA[n8].w;
        accB[n8].x = __expf(accB[n8].x - gB0); sB0 += accB[n8].x;
        accB[n8].y = __expf(accB[n8].y - gB1); sB1 += accB[n8].y;
        accB[n8].z = __expf(accB[n8].z - gB2); sB2 += accB[n8].z;
        accB[n8].w = __expf(accB[n8].w - gB3); sB3 += accB[n8].w;
    }
    #pragma unroll
    for (int off = 8; off; off >>= 1) {
        sA0 += __shfl_xor(sA0, off); sA1 += __shfl_xor(sA1, off);
        sA2 += __shfl_xor(sA2, off); sA3 += __shfl_xor(sA3, off);
        sB0 += __shfl_xor(sB0, off); sB1 += __shfl_xor(sB1, off);
        sB2 += __shfl_xor(sB2, off); sB3 += __shfl_xor(sB3, off);
    }
    if (c16 == 0) {
        redsum[w][g * 4 + 0] = sA0;  redsum[w][g * 4 + 1] = sA1;
        redsum[w][g * 4 + 2] = sA2;  redsum[w][g * 4 + 3] = sA3;
        redsum[w][16 + g * 4 + 0] = sB0;  redsum[w][16 + g * 4 + 1] = sB1;
        redsum[w][16 + g * 4 + 2] = sB2;  redsum[w][16 + g * 4 + 3] = sB3;
    }
    __syncthreads();
#define GSUM(r) (redsum[0][r] + redsum[1][r] + redsum[2][r] + redsum[3][r])
    float iA0 = 1.0f / GSUM(g * 4 + 0), iA1 = 1.0f / GSUM(g * 4 + 1);
    float iA2 = 1.0f / GSUM(g * 4 + 2), iA3 = 1.0f / GSUM(g * 4 + 3);
    float iB0 = 1.0f / GSUM(16 + g * 4 + 0), iB1 = 1.0f / GSUM(16 + g * 4 + 1);
    float iB2 = 1.0f / GSUM(16 + g * 4 + 2), iB3 = 1.0f / GSUM(16 + g * 4 + 3);
#undef GSUM

    #pragma unroll
    for (int n8 = 0; n8 < 8; ++n8) {
        int n = w * 8 + n8;
        float* opA = out + (size_t)(vbase + g * 4) * 512 + n * 16 + c16;
        __builtin_nontemporal_store(accA[n8].x * iA0, opA);
        __builtin_nontemporal_store(accA[n8].y * iA1, opA + 512);
        __builtin_nontemporal_store(accA[n8].z * iA2, opA + 1024);
        __builtin_nontemporal_store(accA[n8].w * iA3, opA + 1536);
        float* opB = opA + 16 * 512;
        __builtin_nontemporal_store(accB[n8].x * iB0, opB);
        __builtin_nontemporal_store(accB[n8].y * iB1, opB + 512);
        __builtin_nontemporal_store(accB[n8].z * iB2, opB + 1024);
        __builtin_nontemporal_store(accB[n8].w * iB3, opB + 1536);
    }
}

extern "C" void kernel_launch(void* const* d_in, const int* in_sizes, int n_in,
                              void* d_out, int out_size, void* d_ws, size_t ws_size,
                              hipStream_t stream) {
    (void)n_in; (void)out_size; (void)ws_size;
    const float* vp  = (const float*)d_in[0];
    const int*   nb1 = (const int*)d_in[1];
    const int*   nb2 = (const int*)d_in[2];
    const float* wv1 = (const float*)d_in[3];
    const float* bv1 = (const float*)d_in[4];
    const float* w1  = (const float*)d_in[5];
    const float* b1  = (const float*)d_in[6];
    const float* wv2 = (const float*)d_in[7];
    const float* bv2 = (const float*)d_in[8];
    const float* w2  = (const float*)d_in[9];
    const float* b2  = (const float*)d_in[10];
    const float* wfc = (const float*)d_in[11];
    const float* bfc = (const float*)d_in[12];
    float* out = (float*)d_out;
    const int V = in_sizes[0];

    float* ws = (float*)d_ws;
    size_t off = 0;
    float* h    = ws + off; off += (size_t)V;
    float* h3   = ws + off; off += (size_t)V * 4;   // 16B aligned
    float* w2t  = ws + off; off += 3 * 32 * 64;
    short* wBh  = (short*)(ws + off); off += 32768 / 2;   // 32768 shorts
    short* wBm  = (short*)(ws + off); off += 32768 / 2;
    short* wBl  = (short*)(ws + off); off += 32768 / 2;

    k_prep<<<(32768 + 6144 + 255) / 256, 256, 0, stream>>>(wfc, w2, wBh, wBm, wBl, w2t);
    kA<<<(V * 32 + 255) / 256, 256, 0, stream>>>(vp, nb1, wv1, bv1, h, V);
    kB<<<(V + 255) / 256, 256, 0, stream>>>(h, h3, V);
    kF<<<V / 32, 256, 0, stream>>>(h3, nb2, w1, b1, wv2, bv2, w2t, b2,
                                   wBh, wBm, wBl, bfc, out, V);
}